// Round 8
// baseline (228.504 us; speedup 1.0000x reference)
//
#include <hip/hip_runtime.h>
#include <hip/hip_bf16.h>

typedef __attribute__((ext_vector_type(8))) short bf16x8;
typedef __attribute__((ext_vector_type(8))) unsigned short u16x8;
typedef __attribute__((ext_vector_type(4))) float f32x4;

#define BM 128
#define NBLK (262144 / BM)   // 2048

// ws layout (bf16 elems, as u16):
//  [0      , 65536) : W1 chunk images: 8 chunks x 8192; chunk kc, elem e: n=e/72, kl=e%72 -> W1[n][kc*64+kl] (zero-pad)
//  [65536  , 73728) : Wtheta [64][128]
//  [73728  , 80896) : piT    [112][64]
#define WS_WT 65536
#define WS_PI 73728
#define PREP_TOT 80896

#define WAIT_LGKM0 asm volatile("s_waitcnt lgkmcnt(0)" ::: "memory")
#define WAIT_VM16  asm volatile("s_waitcnt vmcnt(16)" ::: "memory")
#define WAIT_VM0   asm volatile("s_waitcnt vmcnt(0)" ::: "memory")
#define MEMFENCE   asm volatile("" ::: "memory")
#define SBAR do { __builtin_amdgcn_sched_barrier(0); __builtin_amdgcn_s_barrier(); __builtin_amdgcn_sched_barrier(0); } while (0)

__device__ __forceinline__ unsigned short bfc(float f) {
    union { float f; unsigned u; } v; v.f = f;
    unsigned r = (v.u + 0x7fffu + ((v.u >> 16) & 1u)) >> 16;   // RNE
    return (unsigned short)r;
}

__device__ __forceinline__ unsigned pack2(float a, float b) {
    float2 t; t.x = a; t.y = b;
    __hip_bfloat162 h2 = __float22bfloat162_rn(t);
    union { __hip_bfloat162 h; unsigned u; } v; v.h = h2;
    return v.u;
}

__device__ __forceinline__ unsigned short bf1(float a) {
    __hip_bfloat16 h = __float2bfloat16(a);
    union { __hip_bfloat16 h; unsigned short u; } v; v.h = h;
    return v.u;
}

#define GLLDS16(g, l) __builtin_amdgcn_global_load_lds( \
    (const __attribute__((address_space(1))) void*)(g), \
    (__attribute__((address_space(3))) void*)(l), 16, 0, 0)

__global__ void prep_kernel(const float* __restrict__ W1, const float* __restrict__ Wt,
                            const float* __restrict__ pi, unsigned short* __restrict__ ws) {
    int i = blockIdx.x * 256 + threadIdx.x;
    if (i >= PREP_TOT) return;
    float v = 0.0f;
    if (i < WS_WT) {
        int kc = i >> 13, e = i & 8191;
        int n = e / 72, kl = e - n * 72;
        if (n < 100 && kl < 64) v = W1[n * 512 + (kc << 6) + kl];
    } else if (i < WS_PI) {
        int e = i - WS_WT;
        int n = e >> 7, k = e & 127;
        if (n < 63 && k < 100) v = Wt[n * 100 + k];
    } else {
        int e = i - WS_PI;
        int c = e >> 6, l = e & 63;
        if (c < 100) v = pi[l * 100 + c];
    }
    ws[i] = bfc(v);
}

__global__ __launch_bounds__(256, 3) void treenet_kernel(
    const float* __restrict__ x, const float* __restrict__ b1,
    const float* __restrict__ bth, const unsigned short* __restrict__ ws,
    float* __restrict__ out)
{
    __shared__ __align__(16) unsigned char smem[51200];
    unsigned short* Xl  = (unsigned short*)smem;            // [128][136] bf16 (GEMM1 super-chunk: 128 K-cols)
    unsigned short* W1c = (unsigned short*)(smem + 34816);  // 8192 elems = one W1 chunk image
    unsigned short* Hl  = (unsigned short*)smem;            // [128][136] bf16 (aliases Xl)
    float*          Dl  = (float*)smem;                     // [128][65] f32 (aliases Hl)
    unsigned short* Mul = (unsigned short*)smem;            // [128][72] bf16 (aliases Dl)

    const int tid  = threadIdx.x;
    const int lane = tid & 63;
    const int wv   = tid >> 6;                 // wave 0..3 -> rows wv*32..wv*32+31
    const int lm   = lane & 15;                // A-row / B-col component
    const int lk   = (lane >> 4) << 3;         // per-lane k offset (identical map on A and B)
    const int crow = (wv << 5) + ((lane >> 4) << 2);  // C/D row base (m89 layout)
    const int row0 = blockIdx.x * BM;

    // ---------------- GEMM1: H = relu(X @ W1^T + b1), K=512 in 4 super-chunks of 128 ----------------
    // 512B-contiguous global X extents (lanes 0-31 cover one full 512B row segment per
    // instruction) -> HBM efficiency. W1 per-64-chunk single-buffer gllds (R3-proven),
    // refilled mid-super-chunk. X prefetch loads stay in flight across barriers/MFMA
    // (gllds issued before X loads -> vmcnt(16) drains gllds only).
    const float* xsrc = x + (size_t)row0 * 512;
    float4 XR[16];
    #pragma unroll
    for (int it = 0; it < 16; ++it) {   // prologue: super-chunk 0, 512B extents
        int u = it * 256 + tid; int r = u >> 5, c = u & 31;
        XR[it] = *(const float4*)(xsrc + (size_t)r * 512 + (c << 2));
    }
    f32x4 acc[2][7] = {};

    for (int sc = 0; sc < 4; ++sc) {
        // A. gllds W1 chunk 2*sc (4 ops)
        {
            const unsigned short* srcw = ws + (sc << 14);
            #pragma unroll
            for (int it = 0; it < 4; ++it) { int u = it * 256 + tid; GLLDS16(srcw + (u << 3), W1c + (u << 3)); }
        }
        MEMFENCE;
        // B. stage X super-chunk (16 uint2 ds_writes)
        #pragma unroll
        for (int it = 0; it < 16; ++it) {
            int u = it * 256 + tid; int r = u >> 5, c = u & 31;
            uint2 pk;
            pk.x = pack2(XR[it].x, XR[it].y);
            pk.y = pack2(XR[it].z, XR[it].w);
            *(uint2*)(Xl + r * 136 + (c << 2)) = pk;
        }
        WAIT_LGKM0;   // ds_writes visible
        WAIT_VM0;     // gllds landed (L2-warm, once per super-chunk; no X outstanding here)
        SBAR;
        // C. MFMA half 0 (K cols 0..63 of super-chunk)
        #pragma unroll
        for (int ks = 0; ks < 2; ++ks) {
            const int k0 = (ks << 5) + lk;
            bf16x8 af0 = *(const bf16x8*)(Xl + ((wv << 5) + lm) * 136 + k0);
            bf16x8 af1 = *(const bf16x8*)(Xl + ((wv << 5) + 16 + lm) * 136 + k0);
            #pragma unroll
            for (int fc = 0; fc < 7; ++fc) {
                bf16x8 bf = *(const bf16x8*)(W1c + ((fc << 4) + lm) * 72 + k0);
                acc[0][fc] = __builtin_amdgcn_mfma_f32_16x16x32_bf16(af0, bf, acc[0][fc], 0, 0, 0);
                acc[1][fc] = __builtin_amdgcn_mfma_f32_16x16x32_bf16(af1, bf, acc[1][fc], 0, 0, 0);
            }
        }
        WAIT_LGKM0;
        SBAR;         // W1c free for refill
        // D. gllds W1 chunk 2*sc+1, then next super-chunk X loads (stay in flight)
        {
            const unsigned short* srcw = ws + (sc << 14) + 8192;
            #pragma unroll
            for (int it = 0; it < 4; ++it) { int u = it * 256 + tid; GLLDS16(srcw + (u << 3), W1c + (u << 3)); }
        }
        MEMFENCE;
        if (sc < 3) {
            const float* src = xsrc + ((sc + 1) << 7);
            #pragma unroll
            for (int it = 0; it < 16; ++it) {
                int u = it * 256 + tid; int r = u >> 5, c = u & 31;
                XR[it] = *(const float4*)(src + (size_t)r * 512 + (c << 2));
            }
            WAIT_VM16;   // 4 gllds done; 16 X loads remain in flight
        } else {
            WAIT_VM0;
        }
        SBAR;
        // E. MFMA half 1 (K cols 64..127)
        #pragma unroll
        for (int ks = 2; ks < 4; ++ks) {
            const int k0 = (ks << 5) + lk;
            bf16x8 af0 = *(const bf16x8*)(Xl + ((wv << 5) + lm) * 136 + k0);
            bf16x8 af1 = *(const bf16x8*)(Xl + ((wv << 5) + 16 + lm) * 136 + k0);
            #pragma unroll
            for (int fc = 0; fc < 7; ++fc) {
                bf16x8 bf = *(const bf16x8*)(W1c + ((fc << 4) + lm) * 72 + ((ks & 1) << 5) + lk);
                acc[0][fc] = __builtin_amdgcn_mfma_f32_16x16x32_bf16(af0, bf, acc[0][fc], 0, 0, 0);
                acc[1][fc] = __builtin_amdgcn_mfma_f32_16x16x32_bf16(af1, bf, acc[1][fc], 0, 0, 0);
            }
        }
        WAIT_LGKM0;   // all my LDS reads done -> Xl/W1c may be overwritten next iter
        SBAR;
    }

    // epilogue: bias + relu -> H (bf16) in LDS, K-padded to 128
    #pragma unroll
    for (int fc = 0; fc < 7; ++fc) {
        int c = (fc << 4) + lm;
        float bb = (c < 100) ? b1[c] : 0.0f;
        #pragma unroll
        for (int fr = 0; fr < 2; ++fr)
            #pragma unroll
            for (int r = 0; r < 4; ++r) {
                float h = acc[fr][fc][r] + bb;
                h = h > 0.0f ? h : 0.0f;
                Hl[(crow + (fr << 4) + r) * 136 + c] = bf1(h);
            }
    }
    {   // zero-fill H[:,112..127] (cols 100..127 of B are zero-padded anyway; keep tidy)
        u16x8 z = {0,0,0,0,0,0,0,0};
        *(u16x8*)(Hl + (tid >> 1) * 136 + 112 + ((tid & 1) << 3)) = z;
    }
    __syncthreads();

    // ---------------- GEMM2: D = sigmoid(H @ Wtheta^T + bth), K=128 ----------------
    f32x4 acc2[2][4] = {};
    const unsigned short* Wt = ws + WS_WT;
    #pragma unroll
    for (int ks = 0; ks < 4; ++ks) {
        const int k0 = (ks << 5) + lk;
        bf16x8 af0 = *(const bf16x8*)(Hl + ((wv << 5) + lm) * 136 + k0);
        bf16x8 af1 = *(const bf16x8*)(Hl + ((wv << 5) + 16 + lm) * 136 + k0);
        #pragma unroll
        for (int fc = 0; fc < 4; ++fc) {
            bf16x8 bf = *(const bf16x8*)(Wt + ((fc << 4) + lm) * 128 + k0);
            acc2[0][fc] = __builtin_amdgcn_mfma_f32_16x16x32_bf16(af0, bf, acc2[0][fc], 0, 0, 0);
            acc2[1][fc] = __builtin_amdgcn_mfma_f32_16x16x32_bf16(af1, bf, acc2[1][fc], 0, 0, 0);
        }
    }
    __syncthreads();   // done reading Hl; Dl aliases it
    #pragma unroll
    for (int fc = 0; fc < 4; ++fc) {
        int c = (fc << 4) + lm;
        float bb = (c < 63) ? bth[c] : 0.0f;
        #pragma unroll
        for (int fr = 0; fr < 2; ++fr)
            #pragma unroll
            for (int r = 0; r < 4; ++r) {
                float t = acc2[fr][fc][r] + bb;
                float d = 1.0f / (1.0f + __expf(-t));
                Dl[(crow + (fr << 4) + r) * 65 + c] = d;
            }
    }
    __syncthreads();

    // ---------------- tree products: mu (2 threads per row, 32 leaves each) ----------------
    {
        const int row = tid >> 1, p = tid & 1;
        const float* Dr = Dl + row * 65;
        float d0 = Dr[0];
        float m1 = p ? (1.0f - d0) : d0;
        float dA = Dr[1 + p];
        float m2[2]; m2[0] = m1 * dA; m2[1] = m1 * (1.0f - dA);
        float m4[4];
        #pragma unroll
        for (int i = 0; i < 2; ++i) { float d = Dr[3 + (p << 1) + i];  m4[2*i] = m2[i]*d;  m4[2*i+1] = m2[i]*(1.0f-d); }
        float m8[8];
        #pragma unroll
        for (int i = 0; i < 4; ++i) { float d = Dr[7 + (p << 2) + i];  m8[2*i] = m4[i]*d;  m8[2*i+1] = m4[i]*(1.0f-d); }
        float m16[16];
        #pragma unroll
        for (int i = 0; i < 8; ++i) { float d = Dr[15 + (p << 3) + i]; m16[2*i] = m8[i]*d; m16[2*i+1] = m8[i]*(1.0f-d); }
        float dleaf[16];
        #pragma unroll
        for (int i = 0; i < 16; ++i) dleaf[i] = Dr[31 + (p << 4) + i];
        __syncthreads();   // all reads of Dl complete; Mul may now alias it
        unsigned short* Mr = Mul + row * 72 + (p << 5);
        #pragma unroll
        for (int i = 0; i < 16; ++i) {
            float a = m16[i] * dleaf[i], b = m16[i] * (1.0f - dleaf[i]);
            *(unsigned*)(Mr + (i << 1)) = pack2(a, b);
        }
    }
    __syncthreads();

    // ---------------- GEMM3: out = mu @ pi, K=64 ----------------
    f32x4 acc3[2][7] = {};
    const unsigned short* piT = ws + WS_PI;
    #pragma unroll
    for (int ks = 0; ks < 2; ++ks) {
        const int k0 = (ks << 5) + lk;
        bf16x8 af0 = *(const bf16x8*)(Mul + ((wv << 5) + lm) * 72 + k0);
        bf16x8 af1 = *(const bf16x8*)(Mul + ((wv << 5) + 16 + lm) * 72 + k0);
        #pragma unroll
        for (int fc = 0; fc < 7; ++fc) {
            bf16x8 bf = *(const bf16x8*)(piT + ((fc << 4) + lm) * 64 + k0);
            acc3[0][fc] = __builtin_amdgcn_mfma_f32_16x16x32_bf16(af0, bf, acc3[0][fc], 0, 0, 0);
            acc3[1][fc] = __builtin_amdgcn_mfma_f32_16x16x32_bf16(af1, bf, acc3[1][fc], 0, 0, 0);
        }
    }
    #pragma unroll
    for (int fc = 0; fc < 7; ++fc) {
        int c = (fc << 4) + lm;
        if (c < 100) {
            #pragma unroll
            for (int fr = 0; fr < 2; ++fr)
                #pragma unroll
                for (int r = 0; r < 4; ++r)
                    out[(size_t)(row0 + crow + (fr << 4) + r) * 100 + c] = acc3[fr][fc][r];
        }
    }
}

extern "C" void kernel_launch(void* const* d_in, const int* in_sizes, int n_in,
                              void* d_out, int out_size, void* d_ws, size_t ws_size,
                              hipStream_t stream) {
    const float* x   = (const float*)d_in[0];
    const float* W1  = (const float*)d_in[1];
    const float* b1  = (const float*)d_in[2];
    const float* Wt  = (const float*)d_in[3];
    const float* bth = (const float*)d_in[4];
    const float* pi  = (const float*)d_in[5];
    unsigned short* ws = (unsigned short*)d_ws;

    prep_kernel<<<(PREP_TOT + 255) / 256, 256, 0, stream>>>(W1, Wt, pi, ws);
    treenet_kernel<<<NBLK, 256, 0, stream>>>(x, b1, bth, ws, (float*)d_out);
}

// Round 9
// 172.496 us; speedup vs baseline: 1.3247x; 1.3247x over previous
//
#include <hip/hip_runtime.h>
#include <hip/hip_bf16.h>

typedef __attribute__((ext_vector_type(8))) short bf16x8;
typedef __attribute__((ext_vector_type(8))) unsigned short u16x8;
typedef __attribute__((ext_vector_type(4))) float f32x4;

#define BM 128
#define NBLK (262144 / BM)   // 2048

// ws layout (bf16 elems, as u16):
//  [0      , 65536) : W1 chunk images: 8 chunks x 8192; chunk kc, elem e: n=e/72, kl=e%72 -> W1[n][kc*64+kl] (zero-pad)
//  [65536  , 73728) : Wtheta [64][128]
//  [73728  , 80896) : piT    [112][64]
#define WS_WT 65536
#define WS_PI 73728
#define PREP_TOT 80896

#define WAIT_LGKM0 asm volatile("s_waitcnt lgkmcnt(0)" ::: "memory")
#define WAIT_VM20  asm volatile("s_waitcnt vmcnt(20)" ::: "memory")
#define WAIT_VM12  asm volatile("s_waitcnt vmcnt(12)" ::: "memory")
#define WAIT_VM0   asm volatile("s_waitcnt vmcnt(0)" ::: "memory")
#define MEMFENCE   asm volatile("" ::: "memory")
#define SBAR do { __builtin_amdgcn_sched_barrier(0); __builtin_amdgcn_s_barrier(); __builtin_amdgcn_sched_barrier(0); } while (0)

__device__ __forceinline__ unsigned short bfc(float f) {
    union { float f; unsigned u; } v; v.f = f;
    unsigned r = (v.u + 0x7fffu + ((v.u >> 16) & 1u)) >> 16;   // RNE
    return (unsigned short)r;
}

__device__ __forceinline__ unsigned pack2(float a, float b) {
    float2 t; t.x = a; t.y = b;
    __hip_bfloat162 h2 = __float22bfloat162_rn(t);
    union { __hip_bfloat162 h; unsigned u; } v; v.h = h2;
    return v.u;
}

__device__ __forceinline__ unsigned short bf1(float a) {
    __hip_bfloat16 h = __float2bfloat16(a);
    union { __hip_bfloat16 h; unsigned short u; } v; v.h = h;
    return v.u;
}

#define GLLDS16(g, l) __builtin_amdgcn_global_load_lds( \
    (const __attribute__((address_space(1))) void*)(g), \
    (__attribute__((address_space(3))) void*)(l), 16, 0, 0)

__global__ void prep_kernel(const float* __restrict__ W1, const float* __restrict__ Wt,
                            const float* __restrict__ pi, unsigned short* __restrict__ ws) {
    int i = blockIdx.x * 256 + threadIdx.x;
    if (i >= PREP_TOT) return;
    float v = 0.0f;
    if (i < WS_WT) {
        int kc = i >> 13, e = i & 8191;
        int n = e / 72, kl = e - n * 72;
        if (n < 100 && kl < 64) v = W1[n * 512 + (kc << 6) + kl];
    } else if (i < WS_PI) {
        int e = i - WS_WT;
        int n = e >> 7, k = e & 127;
        if (n < 63 && k < 100) v = Wt[n * 100 + k];
    } else {
        int e = i - WS_PI;
        int c = e >> 6, l = e & 63;
        if (c < 100) v = pi[l * 100 + c];
    }
    ws[i] = bfc(v);
}

// ---- GEMM1 phase macros (R3-proven patterns, parameterized) ----
#define LOADX(A, B, KB_OFF) do { \
    _Pragma("unroll") \
    for (int it = 0; it < 4; ++it) { \
        int u = it * 256 + tid; int r = u >> 3, c8 = u & 7; \
        const float* p = xsrc + (size_t)r * 512 + (KB_OFF) + (c8 << 3); \
        A[it] = *(const float4*)p; \
        B[it] = *(const float4*)(p + 4); \
    } \
} while (0)

#define GLLDSW(KC, BUF) do { \
    const unsigned short* srcw_ = ws + ((KC) << 13); \
    _Pragma("unroll") \
    for (int it = 0; it < 4; ++it) { int u = it * 256 + tid; \
        GLLDS16(srcw_ + (u << 3), (BUF) + (u << 3)); } \
} while (0)

#define STAGEX(A, B) do { \
    _Pragma("unroll") \
    for (int it = 0; it < 4; ++it) { \
        int u = it * 256 + tid; int r = u >> 3, c8 = u & 7; \
        uint4 pk; \
        pk.x = pack2(A[it].x, A[it].y); \
        pk.y = pack2(A[it].z, A[it].w); \
        pk.z = pack2(B[it].x, B[it].y); \
        pk.w = pack2(B[it].z, B[it].w); \
        *(uint4*)(Xl + r * 72 + (c8 << 3)) = pk; \
    } \
} while (0)

#define MFMAPH(WBUF) do { \
    _Pragma("unroll") \
    for (int ks = 0; ks < 2; ++ks) { \
        const int k0 = (ks << 5) + lk; \
        bf16x8 af0 = *(const bf16x8*)(Xl + ((wv << 5) + lm) * 72 + k0); \
        bf16x8 af1 = *(const bf16x8*)(Xl + ((wv << 5) + 16 + lm) * 72 + k0); \
        _Pragma("unroll") \
        for (int fc = 0; fc < 7; ++fc) { \
            bf16x8 bf = *(const bf16x8*)((WBUF) + ((fc << 4) + lm) * 72 + k0); \
            acc[0][fc] = __builtin_amdgcn_mfma_f32_16x16x32_bf16(af0, bf, acc[0][fc], 0, 0, 0); \
            acc[1][fc] = __builtin_amdgcn_mfma_f32_16x16x32_bf16(af1, bf, acc[1][fc], 0, 0, 0); \
        } \
    } \
} while (0)

__global__ __launch_bounds__(256, 3) void treenet_kernel(
    const float* __restrict__ x, const float* __restrict__ b1,
    const float* __restrict__ bth, const unsigned short* __restrict__ ws,
    float* __restrict__ out)
{
    __shared__ __align__(16) unsigned char smem[51200];
    unsigned short* Xl   = (unsigned short*)smem;            // [128][72] bf16 (GEMM1 A-tile)
    unsigned short* W1c0 = (unsigned short*)(smem + 18432);  // 8192 elems (W1 chunk, even)
    unsigned short* W1c1 = (unsigned short*)(smem + 34816);  // 8192 elems (W1 chunk, odd)
    unsigned short* Hl   = (unsigned short*)smem;            // [128][136] bf16 (aliases, after GEMM1)
    float*          Dl   = (float*)smem;                     // [128][65] f32 (aliases Hl)
    unsigned short* Mul  = (unsigned short*)smem;            // [128][72] bf16 (aliases Dl)

    const int tid  = threadIdx.x;
    const int lane = tid & 63;
    const int wv   = tid >> 6;                 // wave 0..3 -> rows wv*32..wv*32+31
    const int lm   = lane & 15;                // A-row / B-col component
    const int lk   = (lane >> 4) << 3;         // per-lane k offset (identical map on A and B)
    const int crow = (wv << 5) + ((lane >> 4) << 2);  // C/D row base (m89 layout)
    const int row0 = blockIdx.x * BM;

    // ---------------- GEMM1: H = relu(X @ W1^T + b1), K=512 in 8 chunks ----------------
    // R3 skeleton + PREFETCH DISTANCE 2: chunk kc's X loads issued at chunk kc-2
    // (~1.5 chunk periods in flight > ~900cy HBM latency -> no stage-entry stall).
    // W1 double-buffered: gllds for kc+1 issued at kc's top (1 period of L2 cover).
    // Issue-order ledger at the per-chunk wait (steady state):
    //   [W1(kc) 4][X(kc+1) 8][W1(kc+1) 4][X(kc+2) 8] = 24 -> vmcnt(20) drains W1(kc) only.
    const float* xsrc = x + (size_t)row0 * 512;
    float4 A0[4], B0[4], A1[4], B1[4];
    LOADX(A0, B0, 0);          // X chunk 0 -> S0
    GLLDSW(0, W1c0);           // W1 chunk 0
    MEMFENCE;
    LOADX(A1, B1, 64);         // X chunk 1 -> S1
    f32x4 acc[2][7] = {};

    #pragma unroll
    for (int i = 0; i < 3; ++i) {           // chunks 0..5, unrolled pairs (static parity)
        const int kc = 2 * i;
        // ---- even chunk kc: S0, W1c0 ----
        GLLDSW(kc + 1, W1c1); MEMFENCE;     // W1 for next chunk
        STAGEX(A0, B0);                     // consumes X(kc) (auto-drained, long arrived)
        LOADX(A0, B0, (kc + 2) << 6);       // X(kc+2) -> S0, in flight 2 periods
        WAIT_LGKM0; WAIT_VM20; SBAR;
        MFMAPH(W1c0);
        WAIT_LGKM0; SBAR;
        // ---- odd chunk kc+1: S1, W1c1 ----
        GLLDSW(kc + 2, W1c0); MEMFENCE;
        STAGEX(A1, B1);
        LOADX(A1, B1, (kc + 3) << 6);       // kc+3 = 3,5,7 all valid
        WAIT_LGKM0; WAIT_VM20; SBAR;
        MFMAPH(W1c1);
        WAIT_LGKM0; SBAR;
    }
    // ---- chunk 6: S0, W1c0 ----
    GLLDSW(7, W1c1); MEMFENCE;
    STAGEX(A0, B0);                         // drains X(6); leaves [W1(6)4][X(7)8][W1(7)4]
    WAIT_LGKM0; WAIT_VM12; SBAR;            // drains W1(6)
    MFMAPH(W1c0);
    WAIT_LGKM0; SBAR;
    // ---- chunk 7: S1, W1c1 ----
    STAGEX(A1, B1);                         // drains X(7); leaves [W1(7)4]
    WAIT_LGKM0; WAIT_VM0; SBAR;
    MFMAPH(W1c1);
    WAIT_LGKM0; SBAR;

    // epilogue: bias + relu -> H (bf16) in LDS, K-padded to 128
    #pragma unroll
    for (int fc = 0; fc < 7; ++fc) {
        int c = (fc << 4) + lm;
        float bb = (c < 100) ? b1[c] : 0.0f;
        #pragma unroll
        for (int fr = 0; fr < 2; ++fr)
            #pragma unroll
            for (int r = 0; r < 4; ++r) {
                float h = acc[fr][fc][r] + bb;
                h = h > 0.0f ? h : 0.0f;
                Hl[(crow + (fr << 4) + r) * 136 + c] = bf1(h);
            }
    }
    {   // zero-fill H[:,112..127]
        u16x8 z = {0,0,0,0,0,0,0,0};
        *(u16x8*)(Hl + (tid >> 1) * 136 + 112 + ((tid & 1) << 3)) = z;
    }
    __syncthreads();

    // ---------------- GEMM2: D = sigmoid(H @ Wtheta^T + bth), K=128 ----------------
    f32x4 acc2[2][4] = {};
    const unsigned short* Wt = ws + WS_WT;
    #pragma unroll
    for (int ks = 0; ks < 4; ++ks) {
        const int k0 = (ks << 5) + lk;
        bf16x8 af0 = *(const bf16x8*)(Hl + ((wv << 5) + lm) * 136 + k0);
        bf16x8 af1 = *(const bf16x8*)(Hl + ((wv << 5) + 16 + lm) * 136 + k0);
        #pragma unroll
        for (int fc = 0; fc < 4; ++fc) {
            bf16x8 bf = *(const bf16x8*)(Wt + ((fc << 4) + lm) * 128 + k0);
            acc2[0][fc] = __builtin_amdgcn_mfma_f32_16x16x32_bf16(af0, bf, acc2[0][fc], 0, 0, 0);
            acc2[1][fc] = __builtin_amdgcn_mfma_f32_16x16x32_bf16(af1, bf, acc2[1][fc], 0, 0, 0);
        }
    }
    __syncthreads();   // done reading Hl; Dl aliases it
    #pragma unroll
    for (int fc = 0; fc < 4; ++fc) {
        int c = (fc << 4) + lm;
        float bb = (c < 63) ? bth[c] : 0.0f;
        #pragma unroll
        for (int fr = 0; fr < 2; ++fr)
            #pragma unroll
            for (int r = 0; r < 4; ++r) {
                float t = acc2[fr][fc][r] + bb;
                float d = 1.0f / (1.0f + __expf(-t));
                Dl[(crow + (fr << 4) + r) * 65 + c] = d;
            }
    }
    __syncthreads();

    // ---------------- tree products: mu (2 threads per row, 32 leaves each) ----------------
    {
        const int row = tid >> 1, p = tid & 1;
        const float* Dr = Dl + row * 65;
        float d0 = Dr[0];
        float m1 = p ? (1.0f - d0) : d0;
        float dA = Dr[1 + p];
        float m2[2]; m2[0] = m1 * dA; m2[1] = m1 * (1.0f - dA);
        float m4[4];
        #pragma unroll
        for (int i = 0; i < 2; ++i) { float d = Dr[3 + (p << 1) + i];  m4[2*i] = m2[i]*d;  m4[2*i+1] = m2[i]*(1.0f-d); }
        float m8[8];
        #pragma unroll
        for (int i = 0; i < 4; ++i) { float d = Dr[7 + (p << 2) + i];  m8[2*i] = m4[i]*d;  m8[2*i+1] = m4[i]*(1.0f-d); }
        float m16[16];
        #pragma unroll
        for (int i = 0; i < 8; ++i) { float d = Dr[15 + (p << 3) + i]; m16[2*i] = m8[i]*d; m16[2*i+1] = m8[i]*(1.0f-d); }
        float dleaf[16];
        #pragma unroll
        for (int i = 0; i < 16; ++i) dleaf[i] = Dr[31 + (p << 4) + i];
        __syncthreads();   // all reads of Dl complete; Mul may now alias it
        unsigned short* Mr = Mul + row * 72 + (p << 5);
        #pragma unroll
        for (int i = 0; i < 16; ++i) {
            float a = m16[i] * dleaf[i], b = m16[i] * (1.0f - dleaf[i]);
            *(unsigned*)(Mr + (i << 1)) = pack2(a, b);
        }
    }
    __syncthreads();

    // ---------------- GEMM3: out = mu @ pi, K=64 ----------------
    f32x4 acc3[2][7] = {};
    const unsigned short* piT = ws + WS_PI;
    #pragma unroll
    for (int ks = 0; ks < 2; ++ks) {
        const int k0 = (ks << 5) + lk;
        bf16x8 af0 = *(const bf16x8*)(Mul + ((wv << 5) + lm) * 72 + k0);
        bf16x8 af1 = *(const bf16x8*)(Mul + ((wv << 5) + 16 + lm) * 72 + k0);
        #pragma unroll
        for (int fc = 0; fc < 7; ++fc) {
            bf16x8 bf = *(const bf16x8*)(piT + ((fc << 4) + lm) * 64 + k0);
            acc3[0][fc] = __builtin_amdgcn_mfma_f32_16x16x32_bf16(af0, bf, acc3[0][fc], 0, 0, 0);
            acc3[1][fc] = __builtin_amdgcn_mfma_f32_16x16x32_bf16(af1, bf, acc3[1][fc], 0, 0, 0);
        }
    }
    #pragma unroll
    for (int fc = 0; fc < 7; ++fc) {
        int c = (fc << 4) + lm;
        if (c < 100) {
            #pragma unroll
            for (int fr = 0; fr < 2; ++fr)
                #pragma unroll
                for (int r = 0; r < 4; ++r)
                    out[(size_t)(row0 + crow + (fr << 4) + r) * 100 + c] = acc3[fr][fc][r];
        }
    }
}

extern "C" void kernel_launch(void* const* d_in, const int* in_sizes, int n_in,
                              void* d_out, int out_size, void* d_ws, size_t ws_size,
                              hipStream_t stream) {
    const float* x   = (const float*)d_in[0];
    const float* W1  = (const float*)d_in[1];
    const float* b1  = (const float*)d_in[2];
    const float* Wt  = (const float*)d_in[3];
    const float* bth = (const float*)d_in[4];
    const float* pi  = (const float*)d_in[5];
    unsigned short* ws = (unsigned short*)d_ws;

    prep_kernel<<<(PREP_TOT + 255) / 256, 256, 0, stream>>>(W1, Wt, pi, ws);
    treenet_kernel<<<NBLK, 256, 0, stream>>>(x, b1, bth, ws, (float*)d_out);
}

// Round 10
// 165.091 us; speedup vs baseline: 1.3841x; 1.0449x over previous
//
#include <hip/hip_runtime.h>
#include <hip/hip_bf16.h>

typedef __attribute__((ext_vector_type(8))) short bf16x8;
typedef __attribute__((ext_vector_type(8))) unsigned short u16x8;
typedef __attribute__((ext_vector_type(4))) float f32x4;

#define BM 128
#define NBLK (262144 / BM)   // 2048

// ws layout (bf16 elems, as u16):
//  [0      , 65536) : W1 chunk images: 8 chunks x 8192; chunk kc, elem e: n=e/72, kl=e%72 -> W1[n][kc*64+kl] (zero-pad)
//  [65536  , 73728) : Wtheta [64][128]
//  [73728  , 80896) : piT    [112][64]
#define WS_WT 65536
#define WS_PI 73728
#define PREP_TOT 80896

#define WAIT_LGKM0 asm volatile("s_waitcnt lgkmcnt(0)" ::: "memory")
#define WAIT_VM8   asm volatile("s_waitcnt vmcnt(8)" ::: "memory")
#define WAIT_VM0   asm volatile("s_waitcnt vmcnt(0)" ::: "memory")
#define MEMFENCE   asm volatile("" ::: "memory")
#define SBAR do { __builtin_amdgcn_sched_barrier(0); __builtin_amdgcn_s_barrier(); __builtin_amdgcn_sched_barrier(0); } while (0)

__device__ __forceinline__ unsigned short bfc(float f) {
    union { float f; unsigned u; } v; v.f = f;
    unsigned r = (v.u + 0x7fffu + ((v.u >> 16) & 1u)) >> 16;   // RNE
    return (unsigned short)r;
}

__device__ __forceinline__ unsigned pack2(float a, float b) {
    float2 t; t.x = a; t.y = b;
    __hip_bfloat162 h2 = __float22bfloat162_rn(t);
    union { __hip_bfloat162 h; unsigned u; } v; v.h = h2;
    return v.u;
}

__device__ __forceinline__ unsigned short bf1(float a) {
    __hip_bfloat16 h = __float2bfloat16(a);
    union { __hip_bfloat16 h; unsigned short u; } v; v.h = h;
    return v.u;
}

#define GLLDS16(g, l) __builtin_amdgcn_global_load_lds( \
    (const __attribute__((address_space(1))) void*)(g), \
    (__attribute__((address_space(3))) void*)(l), 16, 0, 0)

__global__ void prep_kernel(const float* __restrict__ W1, const float* __restrict__ Wt,
                            const float* __restrict__ pi, unsigned short* __restrict__ ws) {
    int i = blockIdx.x * 256 + threadIdx.x;
    if (i >= PREP_TOT) return;
    float v = 0.0f;
    if (i < WS_WT) {
        int kc = i >> 13, e = i & 8191;
        int n = e / 72, kl = e - n * 72;
        if (n < 100 && kl < 64) v = W1[n * 512 + (kc << 6) + kl];
    } else if (i < WS_PI) {
        int e = i - WS_WT;
        int n = e >> 7, k = e & 127;
        if (n < 63 && k < 100) v = Wt[n * 100 + k];
    } else {
        int e = i - WS_PI;
        int c = e >> 6, l = e & 63;
        if (c < 100) v = pi[l * 100 + c];
    }
    ws[i] = bfc(v);
}

__global__ __launch_bounds__(256, 4) void treenet_kernel(
    const float* __restrict__ x, const float* __restrict__ b1,
    const float* __restrict__ bth, const unsigned short* __restrict__ ws,
    float* __restrict__ out)
{
    __shared__ __align__(16) unsigned char smem[51200];
    unsigned short* Xl  = (unsigned short*)smem;            // [128][72] bf16 (GEMM1)
    unsigned short* W1c = (unsigned short*)(smem + 18432);  // 8192 elems (GEMM1)
    unsigned short* Hl  = (unsigned short*)smem;            // [128][136] bf16 (aliases Xl+W1c)
    float*          Dl  = (float*)smem;                     // [128][65] f32  (aliases Hl)
    unsigned short* Mul = (unsigned short*)smem;            // [128][72] bf16 (aliases Dl)
    float*          Cl  = (float*)smem;                     // [128][100] f32 (aliases all, C-stage)

    const int tid  = threadIdx.x;
    const int lane = tid & 63;
    const int wv   = tid >> 6;
    const int lm   = lane & 15;
    const int lk   = (lane >> 4) << 3;
    const int crow = (wv << 5) + ((lane >> 4) << 2);
    const int row0 = blockIdx.x * BM;

    // ---------------- GEMM1: H = relu(X @ W1^T + b1), K=512 in 8 chunks ----------------
    float4 XA[4], XB[4];
    {   // prologue: load chunk 0 into regs
        const float* src = x + (size_t)row0 * 512;
        #pragma unroll
        for (int it = 0; it < 4; ++it) {
            int u = it * 256 + tid; int r = u >> 3, c8 = u & 7;
            const float* p = src + r * 512 + (c8 << 3);
            XA[it] = *(const float4*)p;
            XB[it] = *(const float4*)(p + 4);
        }
    }
    f32x4 acc[2][7] = {};

    for (int kc = 0; kc < 8; ++kc) {
        // 1. issue this chunk's W1 image: global(ws, L2) -> LDS direct (vmcnt +4)
        {
            const unsigned short* src = ws + (kc << 13);
            #pragma unroll
            for (int it = 0; it < 4; ++it) {
                int u = it * 256 + tid;
                GLLDS16(src + (u << 3), W1c + (u << 3));
            }
        }
        MEMFENCE;   // keep gllds issued before everything below
        // 2. stage X regs (cvt_pk) -> LDS
        #pragma unroll
        for (int it = 0; it < 4; ++it) {
            int u = it * 256 + tid; int r = u >> 3, c8 = u & 7;
            uint4 pk;
            pk.x = pack2(XA[it].x, XA[it].y);
            pk.y = pack2(XA[it].z, XA[it].w);
            pk.z = pack2(XB[it].x, XB[it].y);
            pk.w = pack2(XB[it].z, XB[it].w);
            *(uint4*)(Xl + r * 72 + (c8 << 3)) = pk;
        }
        // 3. issue next chunk's X loads NOW (vmcnt +8) — stay in flight across
        //    both barriers and the MFMA phase (counted vmcnt, never drained)
        if (kc < 7) {
            const float* src = x + (size_t)row0 * 512 + ((kc + 1) << 6);
            #pragma unroll
            for (int it = 0; it < 4; ++it) {
                int u = it * 256 + tid; int r = u >> 3, c8 = u & 7;
                const float* p = src + r * 512 + (c8 << 3);
                XA[it] = *(const float4*)p;
                XB[it] = *(const float4*)(p + 4);
            }
            WAIT_LGKM0;           // my ds_writes visible
            WAIT_VM8;             // 4 gllds done; 8 X loads stay in flight
        } else {
            WAIT_LGKM0;
            WAIT_VM0;             // last chunk: drain gllds (no prefetch outstanding)
        }
        SBAR;   // all waves staged
        // 4. MFMA phase
        #pragma unroll
        for (int ks = 0; ks < 2; ++ks) {
            const int k0 = (ks << 5) + lk;
            bf16x8 af0 = *(const bf16x8*)(Xl + ((wv << 5) + lm) * 72 + k0);
            bf16x8 af1 = *(const bf16x8*)(Xl + ((wv << 5) + 16 + lm) * 72 + k0);
            #pragma unroll
            for (int fc = 0; fc < 7; ++fc) {
                bf16x8 bf = *(const bf16x8*)(W1c + ((fc << 4) + lm) * 72 + k0);
                acc[0][fc] = __builtin_amdgcn_mfma_f32_16x16x32_bf16(af0, bf, acc[0][fc], 0, 0, 0);
                acc[1][fc] = __builtin_amdgcn_mfma_f32_16x16x32_bf16(af1, bf, acc[1][fc], 0, 0, 0);
            }
        }
        WAIT_LGKM0;   // my LDS reads complete (frags in regs)
        SBAR;         // all waves done reading; next iter may overwrite (no vm drain)
    }

    // epilogue: bias + relu -> H (bf16) in LDS, K-padded to 128
    #pragma unroll
    for (int fc = 0; fc < 7; ++fc) {
        int c = (fc << 4) + lm;
        float bb = (c < 100) ? b1[c] : 0.0f;
        #pragma unroll
        for (int fr = 0; fr < 2; ++fr)
            #pragma unroll
            for (int r = 0; r < 4; ++r) {
                float h = acc[fr][fc][r] + bb;
                h = h > 0.0f ? h : 0.0f;
                Hl[(crow + (fr << 4) + r) * 136 + c] = bf1(h);
            }
    }
    {   // zero-fill H[:,112..127]
        u16x8 z = {0,0,0,0,0,0,0,0};
        *(u16x8*)(Hl + (tid >> 1) * 136 + 112 + ((tid & 1) << 3)) = z;
    }
    __syncthreads();

    // ---------------- GEMM2: D = sigmoid(H @ Wtheta^T + bth), K=128 ----------------
    f32x4 acc2[2][4] = {};
    const unsigned short* Wt = ws + WS_WT;
    #pragma unroll
    for (int ks = 0; ks < 4; ++ks) {
        const int k0 = (ks << 5) + lk;
        bf16x8 af0 = *(const bf16x8*)(Hl + ((wv << 5) + lm) * 136 + k0);
        bf16x8 af1 = *(const bf16x8*)(Hl + ((wv << 5) + 16 + lm) * 136 + k0);
        #pragma unroll
        for (int fc = 0; fc < 4; ++fc) {
            bf16x8 bf = *(const bf16x8*)(Wt + ((fc << 4) + lm) * 128 + k0);
            acc2[0][fc] = __builtin_amdgcn_mfma_f32_16x16x32_bf16(af0, bf, acc2[0][fc], 0, 0, 0);
            acc2[1][fc] = __builtin_amdgcn_mfma_f32_16x16x32_bf16(af1, bf, acc2[1][fc], 0, 0, 0);
        }
    }
    __syncthreads();   // done reading Hl; Dl aliases it
    #pragma unroll
    for (int fc = 0; fc < 4; ++fc) {
        int c = (fc << 4) + lm;
        float bb = (c < 63) ? bth[c] : 0.0f;
        #pragma unroll
        for (int fr = 0; fr < 2; ++fr)
            #pragma unroll
            for (int r = 0; r < 4; ++r) {
                float t = acc2[fr][fc][r] + bb;
                float d = 1.0f / (1.0f + __expf(-t));
                Dl[(crow + (fr << 4) + r) * 65 + c] = d;
            }
    }
    __syncthreads();

    // ---------------- tree products: mu (2 threads per row, 32 leaves each) ----------------
    {
        const int row = tid >> 1, p = tid & 1;
        const float* Dr = Dl + row * 65;
        float d0 = Dr[0];
        float m1 = p ? (1.0f - d0) : d0;
        float dA = Dr[1 + p];
        float m2[2]; m2[0] = m1 * dA; m2[1] = m1 * (1.0f - dA);
        float m4[4];
        #pragma unroll
        for (int i = 0; i < 2; ++i) { float d = Dr[3 + (p << 1) + i];  m4[2*i] = m2[i]*d;  m4[2*i+1] = m2[i]*(1.0f-d); }
        float m8[8];
        #pragma unroll
        for (int i = 0; i < 4; ++i) { float d = Dr[7 + (p << 2) + i];  m8[2*i] = m4[i]*d;  m8[2*i+1] = m4[i]*(1.0f-d); }
        float m16[16];
        #pragma unroll
        for (int i = 0; i < 8; ++i) { float d = Dr[15 + (p << 3) + i]; m16[2*i] = m8[i]*d; m16[2*i+1] = m8[i]*(1.0f-d); }
        float dleaf[16];
        #pragma unroll
        for (int i = 0; i < 16; ++i) dleaf[i] = Dr[31 + (p << 4) + i];
        __syncthreads();   // all reads of Dl complete; Mul may now alias it
        unsigned short* Mr = Mul + row * 72 + (p << 5);
        #pragma unroll
        for (int i = 0; i < 16; ++i) {
            float a = m16[i] * dleaf[i], b = m16[i] * (1.0f - dleaf[i]);
            *(unsigned*)(Mr + (i << 1)) = pack2(a, b);
        }
    }
    __syncthreads();

    // ---------------- GEMM3: out = mu @ pi, K=64 ----------------
    f32x4 acc3[2][7] = {};
    const unsigned short* piT = ws + WS_PI;
    #pragma unroll
    for (int ks = 0; ks < 2; ++ks) {
        const int k0 = (ks << 5) + lk;
        bf16x8 af0 = *(const bf16x8*)(Mul + ((wv << 5) + lm) * 72 + k0);
        bf16x8 af1 = *(const bf16x8*)(Mul + ((wv << 5) + 16 + lm) * 72 + k0);
        #pragma unroll
        for (int fc = 0; fc < 7; ++fc) {
            bf16x8 bf = *(const bf16x8*)(piT + ((fc << 4) + lm) * 64 + k0);
            acc3[0][fc] = __builtin_amdgcn_mfma_f32_16x16x32_bf16(af0, bf, acc3[0][fc], 0, 0, 0);
            acc3[1][fc] = __builtin_amdgcn_mfma_f32_16x16x32_bf16(af1, bf, acc3[1][fc], 0, 0, 0);
        }
    }
    __syncthreads();   // all waves' Mul reads complete; Cl may alias everything

    // stage C tile in LDS, then fully-dense, sector-aligned 16B stores.
    // (scalar stores at row stride 400B straddle 64B sectors -> L2 write-allocate
    //  FETCHES ~100MB of `out` before overwriting it; dense full-line writes don't)
    #pragma unroll
    for (int fc = 0; fc < 7; ++fc) {
        int c = (fc << 4) + lm;
        if (c < 100) {
            #pragma unroll
            for (int fr = 0; fr < 2; ++fr)
                #pragma unroll
                for (int r = 0; r < 4; ++r)
                    Cl[(crow + (fr << 4) + r) * 100 + c] = acc3[fr][fc][r];
        }
    }
    __syncthreads();
    {   // 128 rows x 100 cols = 3200 float4, block ranges tile `out` exactly
        const float4* Cl4 = (const float4*)Cl;
        float4* o4 = (float4*)(out + (size_t)row0 * 100);
        #pragma unroll
        for (int it = 0; it < 13; ++it) {
            int u = it * 256 + tid;
            if (u < 3200) o4[u] = Cl4[u];
        }
    }
}

extern "C" void kernel_launch(void* const* d_in, const int* in_sizes, int n_in,
                              void* d_out, int out_size, void* d_ws, size_t ws_size,
                              hipStream_t stream) {
    const float* x   = (const float*)d_in[0];
    const float* W1  = (const float*)d_in[1];
    const float* b1  = (const float*)d_in[2];
    const float* Wt  = (const float*)d_in[3];
    const float* bth = (const float*)d_in[4];
    const float* pi  = (const float*)d_in[5];
    unsigned short* ws = (unsigned short*)d_ws;

    prep_kernel<<<(PREP_TOT + 255) / 256, 256, 0, stream>>>(W1, Wt, pi, ws);
    treenet_kernel<<<NBLK, 256, 0, stream>>>(x, b1, bth, ws, (float*)d_out);
}

// Round 11
// 164.580 us; speedup vs baseline: 1.3884x; 1.0031x over previous
//
#include <hip/hip_runtime.h>
#include <hip/hip_bf16.h>

typedef __attribute__((ext_vector_type(8))) short bf16x8;
typedef __attribute__((ext_vector_type(8))) unsigned short u16x8;
typedef __attribute__((ext_vector_type(4))) float f32x4;

#define BM 64
#define NBLK (262144 / BM)   // 4096

// ws layout (bf16 elems, as u16):
//  [0      , 65536) : W1 chunk images: 4 chunks x 16384; chunk kc, elem e: n=e/136, kl=e%136 ->
//                     W1[n][kc*128+kl] if n<100 && kl<128 else 0  (LDS image, stride 136)
//  [65536  , 73728) : Wtheta [64][128]
//  [73728  , 80896) : piT    [112][64]
#define WS_WT 65536
#define WS_PI 73728
#define PREP_TOT 80896

#define WAIT_LGKM0 asm volatile("s_waitcnt lgkmcnt(0)" ::: "memory")
#define WAIT_VM8   asm volatile("s_waitcnt vmcnt(8)" ::: "memory")
#define WAIT_VM0   asm volatile("s_waitcnt vmcnt(0)" ::: "memory")
#define MEMFENCE   asm volatile("" ::: "memory")
#define SBAR do { __builtin_amdgcn_sched_barrier(0); __builtin_amdgcn_s_barrier(); __builtin_amdgcn_sched_barrier(0); } while (0)

__device__ __forceinline__ unsigned short bfc(float f) {
    union { float f; unsigned u; } v; v.f = f;
    unsigned r = (v.u + 0x7fffu + ((v.u >> 16) & 1u)) >> 16;   // RNE
    return (unsigned short)r;
}

__device__ __forceinline__ unsigned pack2(float a, float b) {
    float2 t; t.x = a; t.y = b;
    __hip_bfloat162 h2 = __float22bfloat162_rn(t);
    union { __hip_bfloat162 h; unsigned u; } v; v.h = h2;
    return v.u;
}

__device__ __forceinline__ unsigned short bf1(float a) {
    __hip_bfloat16 h = __float2bfloat16(a);
    union { __hip_bfloat16 h; unsigned short u; } v; v.h = h;
    return v.u;
}

#define GLLDS16(g, l) __builtin_amdgcn_global_load_lds( \
    (const __attribute__((address_space(1))) void*)(g), \
    (__attribute__((address_space(3))) void*)(l), 16, 0, 0)

__global__ void prep_kernel(const float* __restrict__ W1, const float* __restrict__ Wt,
                            const float* __restrict__ pi, unsigned short* __restrict__ ws) {
    int i = blockIdx.x * 256 + threadIdx.x;
    if (i >= PREP_TOT) return;
    float v = 0.0f;
    if (i < WS_WT) {
        int kc = i >> 14, e = i & 16383;
        int n = e / 136, kl = e - n * 136;
        if (n < 100 && kl < 128) v = W1[n * 512 + (kc << 7) + kl];
    } else if (i < WS_PI) {
        int e = i - WS_WT;
        int n = e >> 7, k = e & 127;
        if (n < 63 && k < 100) v = Wt[n * 100 + k];
    } else {
        int e = i - WS_PI;
        int c = e >> 6, l = e & 63;
        if (c < 100) v = pi[l * 100 + c];
    }
    ws[i] = bfc(v);
}

__global__ __launch_bounds__(256, 3) void treenet_kernel(
    const float* __restrict__ x, const float* __restrict__ b1,
    const float* __restrict__ bth, const unsigned short* __restrict__ ws,
    float* __restrict__ out)
{
    __shared__ __align__(16) unsigned char smem[50176];
    unsigned short* Xl  = (unsigned short*)smem;            // [64][136] bf16 (GEMM1 A-tile)
    unsigned short* W1c = (unsigned short*)(smem + 17408);  // 16384 elems (W1 chunk image)
    unsigned short* Hl  = (unsigned short*)smem;            // [64][136] bf16 (aliases Xl)
    float*          Dl  = (float*)smem;                     // [64][68] f32, node i at slot i+1 (aliases Hl)
    unsigned short* Mul = (unsigned short*)(smem + 17408);  // [64][72] bf16 (in W1c region, disjoint from Dl)

    const int tid  = threadIdx.x;
    const int lane = tid & 63;
    const int wv   = tid >> 6;                 // wave 0..3 -> rows wv*16..wv*16+15
    const int lm   = lane & 15;                // A-row / B-col component
    const int lk   = (lane >> 4) << 3;         // per-lane k offset (identical map on A and B)
    const int crow = (wv << 4) + ((lane >> 4) << 2);  // C/D row base (m89 layout, M=16/wave)
    const int row0 = blockIdx.x * BM;

    // ---------------- GEMM1: H = relu(X @ W1^T + b1), K=512 in 4 chunks of 128 ----------------
    // Chunk = 64 rows x 512B/row (vs 128 x 256B): halves the DRAM row-activate rate.
    // Each load instruction covers two fully-dense 512B row segments (lanes 0-31 = one row).
    // Same counted-vmcnt ledger as R3: per chunk [gllds 8][X(kc+1) 8] -> vmcnt(8).
    const float* xsrc = x + (size_t)row0 * 512;
    float4 XR[8];
    #pragma unroll
    for (int it = 0; it < 8; ++it) {   // prologue: chunk 0 (cols 0..127)
        int u = it * 256 + tid; int r = u >> 5, c = u & 31;
        XR[it] = *(const float4*)(xsrc + (size_t)r * 512 + (c << 2));
    }
    f32x4 acc1[7] = {};

    for (int kc = 0; kc < 4; ++kc) {
        // 1. issue this chunk's W1 image: global(ws, L2) -> LDS direct (vmcnt +8)
        {
            const unsigned short* src = ws + (kc << 14);
            #pragma unroll
            for (int it = 0; it < 8; ++it) {
                int u = it * 256 + tid;
                GLLDS16(src + (u << 3), W1c + (u << 3));
            }
        }
        MEMFENCE;
        // 2. stage X regs (cvt_pk) -> LDS  (8B per unit; row r, 16B-col c)
        #pragma unroll
        for (int it = 0; it < 8; ++it) {
            int u = it * 256 + tid; int r = u >> 5, c4 = (u & 31) << 2;
            uint2 pk;
            pk.x = pack2(XR[it].x, XR[it].y);
            pk.y = pack2(XR[it].z, XR[it].w);
            *(uint2*)(Xl + r * 136 + c4) = pk;
        }
        // 3. issue next chunk's X loads NOW — stay in flight across both barriers
        //    and the MFMA phase (counted vmcnt, never drained)
        if (kc < 3) {
            const float* src = xsrc + ((kc + 1) << 7);
            #pragma unroll
            for (int it = 0; it < 8; ++it) {
                int u = it * 256 + tid; int r = u >> 5, c = u & 31;
                XR[it] = *(const float4*)(src + (size_t)r * 512 + (c << 2));
            }
            WAIT_LGKM0;           // my ds_writes visible
            WAIT_VM8;             // 8 gllds done; 8 X loads stay in flight
        } else {
            WAIT_LGKM0;
            WAIT_VM0;             // last chunk: drain gllds
        }
        SBAR;
        // 4. MFMA phase: 4 k-steps x 7 fc
        #pragma unroll
        for (int ks = 0; ks < 4; ++ks) {
            const int k0 = (ks << 5) + lk;
            bf16x8 af = *(const bf16x8*)(Xl + ((wv << 4) + lm) * 136 + k0);
            #pragma unroll
            for (int fc = 0; fc < 7; ++fc) {
                bf16x8 bf = *(const bf16x8*)(W1c + ((fc << 4) + lm) * 136 + k0);
                acc1[fc] = __builtin_amdgcn_mfma_f32_16x16x32_bf16(af, bf, acc1[fc], 0, 0, 0);
            }
        }
        WAIT_LGKM0;   // my LDS reads complete
        SBAR;         // all waves done; next iter may overwrite
    }

    // epilogue: bias + relu -> H (bf16) in LDS, K-padded to 128
    #pragma unroll
    for (int fc = 0; fc < 7; ++fc) {
        int c = (fc << 4) + lm;
        float bb = (c < 100) ? b1[c] : 0.0f;
        #pragma unroll
        for (int r = 0; r < 4; ++r) {
            float h = acc1[fc][r] + bb;
            h = h > 0.0f ? h : 0.0f;
            Hl[(crow + r) * 136 + c] = bf1(h);
        }
    }
    {   // zero-fill H[:,112..127]: 64 rows x 16 cols, 4 bf16 (8B) per thread
        uint2 z; z.x = 0; z.y = 0;
        *(uint2*)(Hl + (tid >> 2) * 136 + 112 + ((tid & 3) << 2)) = z;
    }
    __syncthreads();

    // ---------------- GEMM2: D = sigmoid(H @ Wtheta^T + bth), K=128 ----------------
    f32x4 acc2[4] = {};
    const unsigned short* Wt = ws + WS_WT;
    #pragma unroll
    for (int ks = 0; ks < 4; ++ks) {
        const int k0 = (ks << 5) + lk;
        bf16x8 af = *(const bf16x8*)(Hl + ((wv << 4) + lm) * 136 + k0);
        #pragma unroll
        for (int fc = 0; fc < 4; ++fc) {
            bf16x8 bf = *(const bf16x8*)(Wt + ((fc << 4) + lm) * 128 + k0);
            acc2[fc] = __builtin_amdgcn_mfma_f32_16x16x32_bf16(af, bf, acc2[fc], 0, 0, 0);
        }
    }
    __syncthreads();   // done reading Hl; Dl aliases it
    // D epilogue: node c stored at aligned slot c+1 (level L starts at slot 2^L)
    #pragma unroll
    for (int fc = 0; fc < 4; ++fc) {
        int c = (fc << 4) + lm;
        float bb = (c < 63) ? bth[c] : 0.0f;
        #pragma unroll
        for (int r = 0; r < 4; ++r) {
            float t = acc2[fc][r] + bb;
            float d = 1.0f / (1.0f + __expf(-t));
            if (c < 63) Dl[(crow + r) * 68 + 1 + c] = d;
        }
    }
    __syncthreads();

    // ---------------- tree products: mu (4 threads per row, 16 leaves each) ----------------
    {
        const int row = tid >> 2, p = tid & 3;      // leaves l = 16p + i, i in 0..15
        const float* Dr = Dl + row * 68;
        float d0 = Dr[1];                            // level0 (root), bit = p>>1
        float d1 = Dr[2 + (p >> 1)];                 // level1, bit = p&1
        float d2 = Dr[4 + p];                        // level2, bit = i>>3
        float m1 = ((p >> 1) ? (1.0f - d0) : d0) * ((p & 1) ? (1.0f - d1) : d1);
        float m2[2]; m2[0] = m1 * d2; m2[1] = m1 * (1.0f - d2);
        float2 d3 = *(const float2*)(Dr + 8 + (p << 1));      // level3, aligned 8B
        float m3[4];
        #pragma unroll
        for (int j = 0; j < 2; ++j) { float d = (j ? d3.y : d3.x); m3[2*j] = m2[j]*d; m3[2*j+1] = m2[j]*(1.0f-d); }
        float4 d4 = *(const float4*)(Dr + 16 + (p << 2));     // level4, aligned 16B
        float m4[8];
        { m4[0]=m3[0]*d4.x; m4[1]=m3[0]*(1.0f-d4.x); m4[2]=m3[1]*d4.y; m4[3]=m3[1]*(1.0f-d4.y);
          m4[4]=m3[2]*d4.z; m4[5]=m3[2]*(1.0f-d4.z); m4[6]=m3[3]*d4.w; m4[7]=m3[3]*(1.0f-d4.w); }
        float4 d5a = *(const float4*)(Dr + 32 + (p << 3));    // level5 (8 floats, aligned)
        float4 d5b = *(const float4*)(Dr + 36 + (p << 3));
        float d5[8] = {d5a.x, d5a.y, d5a.z, d5a.w, d5b.x, d5b.y, d5b.z, d5b.w};
        unsigned short* Mr = Mul + row * 72 + (p << 4);
        #pragma unroll
        for (int j = 0; j < 8; ++j) {
            float a = m4[j] * d5[j], b = m4[j] * (1.0f - d5[j]);
            *(unsigned*)(Mr + (j << 1)) = pack2(a, b);
        }
    }
    __syncthreads();

    // ---------------- GEMM3: out = mu @ pi, K=64 ----------------
    f32x4 acc3[7] = {};
    const unsigned short* piT = ws + WS_PI;
    #pragma unroll
    for (int ks = 0; ks < 2; ++ks) {
        const int k0 = (ks << 5) + lk;
        bf16x8 af = *(const bf16x8*)(Mul + ((wv << 4) + lm) * 72 + k0);
        #pragma unroll
        for (int fc = 0; fc < 7; ++fc) {
            bf16x8 bf = *(const bf16x8*)(piT + ((fc << 4) + lm) * 64 + k0);
            acc3[fc] = __builtin_amdgcn_mfma_f32_16x16x32_bf16(af, bf, acc3[fc], 0, 0, 0);
        }
    }
    #pragma unroll
    for (int fc = 0; fc < 7; ++fc) {
        int c = (fc << 4) + lm;
        if (c < 100) {
            #pragma unroll
            for (int r = 0; r < 4; ++r)
                out[(size_t)(row0 + crow + r) * 100 + c] = acc3[fc][r];
        }
    }
}

extern "C" void kernel_launch(void* const* d_in, const int* in_sizes, int n_in,
                              void* d_out, int out_size, void* d_ws, size_t ws_size,
                              hipStream_t stream) {
    const float* x   = (const float*)d_in[0];
    const float* W1  = (const float*)d_in[1];
    const float* b1  = (const float*)d_in[2];
    const float* Wt  = (const float*)d_in[3];
    const float* bth = (const float*)d_in[4];
    const float* pi  = (const float*)d_in[5];
    unsigned short* ws = (unsigned short*)d_ws;

    prep_kernel<<<(PREP_TOT + 255) / 256, 256, 0, stream>>>(W1, Wt, pi, ws);
    treenet_kernel<<<NBLK, 256, 0, stream>>>(x, b1, bth, ws, (float*)d_out);
}